// Round 11
// baseline (89.249 us; speedup 1.0000x reference)
//
#include <hip/hip_runtime.h>
#include <hip/hip_bf16.h>

#define BS 512
#define MARGIN 0.5f
#define NBLK 512

using short8 = __attribute__((ext_vector_type(8))) short;
using f32x4 = __attribute__((ext_vector_type(4))) float;

__device__ inline short bf16_rne(float x) {
    __hip_bfloat16 h = __float2bfloat16(x);
    return *(short*)&h;
}

// One fused kernel. Grid 512 x 256 (all blocks co-resident: 2/CU << capacity).
// Phase A: full 512x512 dist via 16x16 MFMA tiles (waves 0,1: tile t=b*2+w),
//          fused in-register norms; block 0 wave 3 compacts pos/neg lists.
// Barrier: device-scope arrive counter + poll (threadfence both sides).
// Phase C: hinge per pos-anchor b (readlane j-broadcast, ballot count).
// Phase D: done counter; last block reduces 512 partials, writes out.
__global__ __launch_bounds__(256) void kfused(
    const float* __restrict__ pred, const int* __restrict__ target,
    float* __restrict__ dist, int* __restrict__ plist, int* __restrict__ nlist,
    int* __restrict__ counts, float* __restrict__ psum, float* __restrict__ pcnt,
    unsigned int* __restrict__ bar, unsigned int* __restrict__ fin,
    float* __restrict__ out)
{
    const int b = blockIdx.x;
    const int tid = threadIdx.x;
    const int lane = tid & 63;
    const int w = tid >> 6;

    // ---------------- Phase A ----------------
    if (w < 2) {
        const int t = b * 2 + w;      // 0..1023 tile id
        const int trow = t >> 5;      // 0..31
        const int tcol = t & 31;      // 0..31
        const int rl = lane & 15;
        const int koff = (lane >> 4) * 8;
        const float* A = pred + (trow * 16 + rl) * BS;
        const float* B = pred + (tcol * 16 + rl) * BS;
        f32x4 acc = {0.f, 0.f, 0.f, 0.f};
        float na = 0.f, nb = 0.f;
#pragma unroll 4
        for (int ks = 0; ks < 16; ++ks) {
            const int k = ks * 32 + koff;
            const f32x4 al = *(const f32x4*)(A + k);
            const f32x4 ah = *(const f32x4*)(A + k + 4);
            const f32x4 bl = *(const f32x4*)(B + k);
            const f32x4 bh = *(const f32x4*)(B + k + 4);
            short8 a8, b8;
#pragma unroll
            for (int j = 0; j < 4; ++j) {
                na += al[j] * al[j] + ah[j] * ah[j];
                nb += bl[j] * bl[j] + bh[j] * bh[j];
                a8[j] = bf16_rne(al[j]); a8[4 + j] = bf16_rne(ah[j]);
                b8[j] = bf16_rne(bl[j]); b8[4 + j] = bf16_rne(bh[j]);
            }
            acc = __builtin_amdgcn_mfma_f32_16x16x32_bf16(a8, b8, acc, 0, 0, 0);
        }
        na += __shfl_xor(na, 16, 64); na += __shfl_xor(na, 32, 64);
        nb += __shfl_xor(nb, 16, 64); nb += __shfl_xor(nb, 32, 64);
        const float ia = 1.0f / fmaxf(sqrtf(na), 1e-10f);
        const float ib = 1.0f / fmaxf(sqrtf(nb), 1e-10f);
        // C/D layout: col = lane&15, row = (lane>>4)*4 + reg  [m89]
        const int rbase = (lane >> 4) * 4;
        const int gcol = tcol * 16 + rl;
#pragma unroll
        for (int r = 0; r < 4; ++r) {
            const float irow = __shfl(ia, rbase + r, 64);
            const int grow = trow * 16 + rbase + r;
            float d2 = 2.0f - 2.0f * acc[r] * irow * ib;
            dist[grow * BS + gcol] = sqrtf(fmaxf(d2, 0.f));
        }
    } else if (b == 0 && w == 3) {
        // stable compaction of positives / negatives (one wave)
        int pbase = 0, nbase = 0;
#pragma unroll
        for (int c = 0; c < 8; ++c) {
            const int idx = c * 64 + lane;
            const int tg = target[idx];
            const unsigned long long mp = __ballot(tg == 1);
            const unsigned long long mn = __ballot(tg == 0);
            const unsigned long long below = (1ULL << lane) - 1ULL;
            if (tg == 1) plist[pbase + __popcll(mp & below)] = idx;
            else         nlist[nbase + __popcll(mn & below)] = idx;
            pbase += __popcll(mp);
            nbase += __popcll(mn);
        }
        if (lane == 0) { counts[0] = pbase; counts[1] = nbase; }
    }

    // ---------------- device-wide barrier ----------------
    __syncthreads();
    if (tid == 0) {
        __threadfence();  // release: dist / lists visible device-wide
        atomicAdd(bar, 1u);
        while (__hip_atomic_load(bar, __ATOMIC_RELAXED, __HIP_MEMORY_SCOPE_AGENT) < NBLK)
            __builtin_amdgcn_s_sleep(8);
    }
    __syncthreads();
    __threadfence();  // acquire

    // ---------------- Phase C: hinge ----------------
    const int npos = counts[0];
    const int nneg = counts[1];
    __shared__ float sbuf[4];
    __shared__ float cbuf[4];
    __shared__ unsigned int slast;

    float sum = 0.f;
    unsigned int cw = 0;

    if (b < npos) {
        const float* drow = dist + plist[b] * BS;
        // k-role: this thread's negatives (gathered), sentinel +1e30
        const float bv0 = (tid < nneg) ? drow[nlist[tid]] : 1e30f;
        const float bv1 = (tid + 256 < nneg) ? drow[nlist[tid + 256]] : 1e30f;
        // j-role: wave w owns chunks w and w+4 of compacted positives
        const int ja = w * 64 + lane;
        const int jb2 = (w + 4) * 64 + lane;
        const float av0 = (ja < npos && ja != b) ? drow[plist[ja]] + MARGIN : -1e9f;
        const float av1 = (jb2 < npos && jb2 != b) ? drow[plist[jb2]] + MARGIN : -1e9f;

#define HINGE(TJ, BK)                                       \
    do {                                                    \
        const float v_ = (TJ) - (BK);                       \
        sum += fmaxf(v_, 0.f);                              \
        cw += (unsigned int)__popcll(__ballot(v_ > 0.f));   \
    } while (0)

        if (nneg > 256) {  // uniform rare path
            if (w * 64 < npos) {
#pragma unroll 8
                for (int jj = 0; jj < 64; ++jj) {
                    const float tj = __int_as_float(
                        __builtin_amdgcn_readlane(__float_as_int(av0), jj));
                    HINGE(tj, bv0); HINGE(tj, bv1);
                }
            }
            if ((w + 4) * 64 < npos) {
#pragma unroll 8
                for (int jj = 0; jj < 64; ++jj) {
                    const float tj = __int_as_float(
                        __builtin_amdgcn_readlane(__float_as_int(av1), jj));
                    HINGE(tj, bv0); HINGE(tj, bv1);
                }
            }
        } else {  // typical: nneg <= 256
            if (w * 64 < npos) {
#pragma unroll 8
                for (int jj = 0; jj < 64; ++jj) {
                    const float tj = __int_as_float(
                        __builtin_amdgcn_readlane(__float_as_int(av0), jj));
                    HINGE(tj, bv0);
                }
            }
            if ((w + 4) * 64 < npos) {
#pragma unroll 8
                for (int jj = 0; jj < 64; ++jj) {
                    const float tj = __int_as_float(
                        __builtin_amdgcn_readlane(__float_as_int(av1), jj));
                    HINGE(tj, bv0);
                }
            }
        }
#undef HINGE
    }

    float wsm = sum;
#pragma unroll
    for (int o = 32; o > 0; o >>= 1) wsm += __shfl_xor(wsm, o, 64);
    if (lane == 0) { sbuf[w] = wsm; cbuf[w] = (float)cw; }
    __syncthreads();
    if (tid == 0) {
        psum[b] = (sbuf[0] + sbuf[1]) + (sbuf[2] + sbuf[3]);
        pcnt[b] = (cbuf[0] + cbuf[1]) + (cbuf[2] + cbuf[3]);
    }

    // ---------------- Phase D: finalize ----------------
    if (tid == 0) {
        __threadfence();  // release partials
        slast = (atomicAdd(fin, 1u) == (unsigned int)(NBLK - 1)) ? 1u : 0u;
    }
    __syncthreads();
    if (slast != 0 && tid < 64) {
        __threadfence();  // acquire
        float s = 0.f, c = 0.f;
#pragma unroll
        for (int r = 0; r < 8; ++r) {
            s += psum[r * 64 + tid];
            c += pcnt[r * 64 + tid];
        }
#pragma unroll
        for (int o = 32; o > 0; o >>= 1) {
            s += __shfl_xor(s, o, 64);
            c += __shfl_xor(c, o, 64);
        }
        if (tid == 0) out[0] = s / (c + 1e-7f);
    }
}

extern "C" void kernel_launch(void* const* d_in, const int* in_sizes, int n_in,
                              void* d_out, int out_size, void* d_ws, size_t ws_size,
                              hipStream_t stream) {
    const float* pred = (const float*)d_in[0];
    const int* target = (const int*)d_in[1];
    float* out = (float*)d_out;
    char* base = (char*)d_ws;

    float* dist = (float*)base;                       // 1 MB (full 512x512)
    int* plist = (int*)(base + 1048576);              // 2 KB
    int* nlist = (int*)(base + 1050624);              // 2 KB
    int* counts = (int*)(base + 1052672);             // 64 B
    float* psum = (float*)(base + 1052736);           // 2 KB
    float* pcnt = (float*)(base + 1054784);           // 2 KB
    unsigned int* bar = (unsigned int*)(base + 1056832);
    unsigned int* fin = (unsigned int*)(base + 1056960);

    // zero both counters (one small DMA fill; graph-capture-legal)
    hipMemsetAsync((void*)(base + 1056832), 0, 192, stream);
    kfused<<<NBLK, 256, 0, stream>>>(pred, target, dist, plist, nlist, counts,
                                     psum, pcnt, bar, fin, out);
}

// Round 12
// 31.867 us; speedup vs baseline: 2.8006x; 2.8006x over previous
//
#include <hip/hip_runtime.h>
#include <hip/hip_bf16.h>

#define BS 512
#define MARGIN 0.5f
#define NBLK 512

using short8 = __attribute__((ext_vector_type(8))) short;
using f32x4 = __attribute__((ext_vector_type(4))) float;

__device__ inline short bf16_rne(float x) {
    __hip_bfloat16 h = __float2bfloat16(x);
    return *(short*)&h;
}

// Kernel 1: full dist[i][j] = sqrt(max(2 - 2*dot*inv_i*inv_j, 0)), bf16 MFMA,
// fused in-register norms. One wave per 32x32 tile, 256 blocks x 64 thr.
__global__ __launch_bounds__(64) void kdistf(const float* __restrict__ pred,
                                             float* __restrict__ dist) {
    const int lane = threadIdx.x;
    const int r0 = blockIdx.y * 32;
    const int c0 = blockIdx.x * 32;
    const int rl = lane & 15;
    const int koff = (lane >> 4) * 8;

    const float* A0 = pred + (r0 + rl) * BS;
    const float* A1 = pred + (r0 + 16 + rl) * BS;
    const float* B0 = pred + (c0 + rl) * BS;
    const float* B1 = pred + (c0 + 16 + rl) * BS;

    f32x4 acc00 = {0.f, 0.f, 0.f, 0.f};
    f32x4 acc01 = {0.f, 0.f, 0.f, 0.f};
    f32x4 acc10 = {0.f, 0.f, 0.f, 0.f};
    f32x4 acc11 = {0.f, 0.f, 0.f, 0.f};
    float na0 = 0.f, na1 = 0.f, nb0 = 0.f, nb1 = 0.f;

#pragma unroll 4
    for (int ks = 0; ks < 16; ++ks) {
        const int k = ks * 32 + koff;
        const f32x4 a0l = *(const f32x4*)(A0 + k);
        const f32x4 a0h = *(const f32x4*)(A0 + k + 4);
        const f32x4 a1l = *(const f32x4*)(A1 + k);
        const f32x4 a1h = *(const f32x4*)(A1 + k + 4);
        const f32x4 b0l = *(const f32x4*)(B0 + k);
        const f32x4 b0h = *(const f32x4*)(B0 + k + 4);
        const f32x4 b1l = *(const f32x4*)(B1 + k);
        const f32x4 b1h = *(const f32x4*)(B1 + k + 4);

        short8 sa0, sa1, sb0, sb1;
#pragma unroll
        for (int j = 0; j < 4; ++j) {
            na0 += a0l[j] * a0l[j] + a0h[j] * a0h[j];
            na1 += a1l[j] * a1l[j] + a1h[j] * a1h[j];
            nb0 += b0l[j] * b0l[j] + b0h[j] * b0h[j];
            nb1 += b1l[j] * b1l[j] + b1h[j] * b1h[j];
            sa0[j] = bf16_rne(a0l[j]); sa0[4 + j] = bf16_rne(a0h[j]);
            sa1[j] = bf16_rne(a1l[j]); sa1[4 + j] = bf16_rne(a1h[j]);
            sb0[j] = bf16_rne(b0l[j]); sb0[4 + j] = bf16_rne(b0h[j]);
            sb1[j] = bf16_rne(b1l[j]); sb1[4 + j] = bf16_rne(b1h[j]);
        }
        acc00 = __builtin_amdgcn_mfma_f32_16x16x32_bf16(sa0, sb0, acc00, 0, 0, 0);
        acc01 = __builtin_amdgcn_mfma_f32_16x16x32_bf16(sa0, sb1, acc01, 0, 0, 0);
        acc10 = __builtin_amdgcn_mfma_f32_16x16x32_bf16(sa1, sb0, acc10, 0, 0, 0);
        acc11 = __builtin_amdgcn_mfma_f32_16x16x32_bf16(sa1, sb1, acc11, 0, 0, 0);
    }

    na0 += __shfl_xor(na0, 16, 64); na0 += __shfl_xor(na0, 32, 64);
    na1 += __shfl_xor(na1, 16, 64); na1 += __shfl_xor(na1, 32, 64);
    nb0 += __shfl_xor(nb0, 16, 64); nb0 += __shfl_xor(nb0, 32, 64);
    nb1 += __shfl_xor(nb1, 16, 64); nb1 += __shfl_xor(nb1, 32, 64);
    const float ia0 = 1.0f / fmaxf(sqrtf(na0), 1e-10f);
    const float ia1 = 1.0f / fmaxf(sqrtf(na1), 1e-10f);
    const float ib0 = 1.0f / fmaxf(sqrtf(nb0), 1e-10f);
    const float ib1 = 1.0f / fmaxf(sqrtf(nb1), 1e-10f);

    // C/D layout: col = lane&15, row = (lane>>4)*4 + reg  [m89]
    const int rbase = (lane >> 4) * 4;
#pragma unroll
    for (int fr = 0; fr < 2; ++fr) {
        const float iaSel = (fr == 0) ? ia0 : ia1;
#pragma unroll
        for (int fc = 0; fc < 2; ++fc) {
            f32x4 v = (fr == 0) ? (fc == 0 ? acc00 : acc01) : (fc == 0 ? acc10 : acc11);
            const int col = c0 + fc * 16 + rl;
            const float icol = (fc == 0) ? ib0 : ib1;
#pragma unroll
            for (int r = 0; r < 4; ++r) {
                const float irow = __shfl(iaSel, rbase + r, 64);
                const int row = r0 + fr * 16 + rbase + r;
                float d2 = 2.0f - 2.0f * v[r] * irow * icol;
                dist[row * BS + col] = sqrtf(fmaxf(d2, 0.f));
            }
        }
    }
}

// Kernel 2: block b = pos-space anchor. Wave 0 compacts pos/neg lists into LDS
// (no global list dependency). Hinge via readlane j-broadcast + ballot count.
// Done-counter tail: last block reduces all 512 partials and writes out.
__global__ __launch_bounds__(256) void ktri(const float* __restrict__ dist,
                                            const int* __restrict__ target,
                                            float* __restrict__ psum,
                                            float* __restrict__ pcnt,
                                            unsigned int* __restrict__ fin,
                                            float* __restrict__ out) {
    const int b = blockIdx.x;
    const int tid = threadIdx.x;
    const int lane = tid & 63;
    const int w = tid >> 6;
    __shared__ int plist[BS];
    __shared__ int nlist[BS];
    __shared__ int cnts[2];
    __shared__ float sbuf[4];
    __shared__ float cbuf[4];
    __shared__ unsigned int slast;

    if (w == 0) {  // one-wave stable compaction into LDS
        int pbase = 0, nbase = 0;
#pragma unroll
        for (int c = 0; c < 8; ++c) {
            const int idx = c * 64 + lane;
            const int tg = target[idx];
            const unsigned long long mp = __ballot(tg == 1);
            const unsigned long long mn = __ballot(tg == 0);
            const unsigned long long below = (1ULL << lane) - 1ULL;
            if (tg == 1) plist[pbase + __popcll(mp & below)] = idx;
            else         nlist[nbase + __popcll(mn & below)] = idx;
            pbase += __popcll(mp);
            nbase += __popcll(mn);
        }
        if (lane == 0) { cnts[0] = pbase; cnts[1] = nbase; }
    }
    __syncthreads();
    const int npos = cnts[0];
    const int nneg = cnts[1];

    float sum = 0.f;
    unsigned int cw = 0;

    if (b < npos) {
        const float* drow = dist + plist[b] * BS;
        // k-role: this thread's negatives (LDS index, global gather), +1e30 pad
        const float bv0 = (tid < nneg) ? drow[nlist[tid]] : 1e30f;
        const float bv1 = (tid + 256 < nneg) ? drow[nlist[tid + 256]] : 1e30f;
        // j-role: wave w owns chunks w and w+4 of compacted positives
        const int ja = w * 64 + lane;
        const int jb2 = (w + 4) * 64 + lane;
        const float av0 = (ja < npos && ja != b) ? drow[plist[ja]] + MARGIN : -1e9f;
        const float av1 = (jb2 < npos && jb2 != b) ? drow[plist[jb2]] + MARGIN : -1e9f;

#define HINGE(TJ, BK)                                       \
    do {                                                    \
        const float v_ = (TJ) - (BK);                       \
        sum += fmaxf(v_, 0.f);                              \
        cw += (unsigned int)__popcll(__ballot(v_ > 0.f));   \
    } while (0)

        if (nneg > 256) {  // uniform rare path
            if (w * 64 < npos) {
#pragma unroll 8
                for (int jj = 0; jj < 64; ++jj) {
                    const float tj = __int_as_float(
                        __builtin_amdgcn_readlane(__float_as_int(av0), jj));
                    HINGE(tj, bv0); HINGE(tj, bv1);
                }
            }
            if ((w + 4) * 64 < npos) {
#pragma unroll 8
                for (int jj = 0; jj < 64; ++jj) {
                    const float tj = __int_as_float(
                        __builtin_amdgcn_readlane(__float_as_int(av1), jj));
                    HINGE(tj, bv0); HINGE(tj, bv1);
                }
            }
        } else {  // typical: nneg <= 256
            if (w * 64 < npos) {
#pragma unroll 8
                for (int jj = 0; jj < 64; ++jj) {
                    const float tj = __int_as_float(
                        __builtin_amdgcn_readlane(__float_as_int(av0), jj));
                    HINGE(tj, bv0);
                }
            }
            if ((w + 4) * 64 < npos) {
#pragma unroll 8
                for (int jj = 0; jj < 64; ++jj) {
                    const float tj = __int_as_float(
                        __builtin_amdgcn_readlane(__float_as_int(av1), jj));
                    HINGE(tj, bv0);
                }
            }
        }
#undef HINGE
    }

    float wsm = sum;
#pragma unroll
    for (int o = 32; o > 0; o >>= 1) wsm += __shfl_xor(wsm, o, 64);
    if (lane == 0) { sbuf[w] = wsm; cbuf[w] = (float)cw; }
    __syncthreads();
    if (tid == 0) {
        psum[b] = (sbuf[0] + sbuf[1]) + (sbuf[2] + sbuf[3]);
        pcnt[b] = (cbuf[0] + cbuf[1]) + (cbuf[2] + cbuf[3]);
        __threadfence();  // release partials
        slast = (atomicAdd(fin, 1u) == (unsigned int)(NBLK - 1)) ? 1u : 0u;
    }
    __syncthreads();
    if (slast != 0 && tid < 64) {
        __threadfence();  // acquire
        float s = 0.f, c = 0.f;
#pragma unroll
        for (int r = 0; r < 8; ++r) {
            s += psum[r * 64 + tid];
            c += pcnt[r * 64 + tid];
        }
#pragma unroll
        for (int o = 32; o > 0; o >>= 1) {
            s += __shfl_xor(s, o, 64);
            c += __shfl_xor(c, o, 64);
        }
        if (tid == 0) out[0] = s / (c + 1e-7f);
    }
}

extern "C" void kernel_launch(void* const* d_in, const int* in_sizes, int n_in,
                              void* d_out, int out_size, void* d_ws, size_t ws_size,
                              hipStream_t stream) {
    const float* pred = (const float*)d_in[0];
    const int* target = (const int*)d_in[1];
    float* out = (float*)d_out;
    char* base = (char*)d_ws;

    float* dist = (float*)base;               // 1 MB (full 512x512)
    float* psum = (float*)(base + 1048576);   // 2 KB
    float* pcnt = (float*)(base + 1050624);   // 2 KB
    unsigned int* fin = (unsigned int*)(base + 1052672);

    hipMemsetAsync((void*)fin, 0, 64, stream);
    dim3 gb(16, 16);
    kdistf<<<gb, 64, 0, stream>>>(pred, dist);
    ktri<<<NBLK, 256, 0, stream>>>(dist, target, psum, pcnt, fin, out);
}

// Round 13
// 28.164 us; speedup vs baseline: 3.1689x; 1.1315x over previous
//
#include <hip/hip_runtime.h>
#include <hip/hip_bf16.h>

#define BS 512
#define MARGIN 0.5f
#define NBLK 512

using short8 = __attribute__((ext_vector_type(8))) short;
using f32x4 = __attribute__((ext_vector_type(4))) float;

__device__ inline short bf16_rne(float x) {
    __hip_bfloat16 h = __float2bfloat16(x);
    return *(short*)&h;
}

// Kernel 1: dist rows for POSITIVE anchors (pos-space rows) x all 512 cols.
// One wave per 32x32 tile. Each block does its own in-wave compaction (LDS
// plist) -- no setup kernel. Block (0,0) zeroes fin for kernel 2's tail.
__global__ __launch_bounds__(64) void kdistf(const float* __restrict__ pred,
                                             const int* __restrict__ target,
                                             float* __restrict__ dist,
                                             unsigned int* __restrict__ fin) {
    const int lane = threadIdx.x;
    if (blockIdx.x == 0 && blockIdx.y == 0 && lane == 0) *fin = 0u;
    __shared__ int plist[BS];

    // one-wave stable compaction of positives into LDS
    int pbase = 0;
    const unsigned long long below = (1ULL << lane) - 1ULL;
#pragma unroll
    for (int c = 0; c < 8; ++c) {
        const int idx = c * 64 + lane;
        const int tg = target[idx];
        const unsigned long long mp = __ballot(tg == 1);
        if (tg == 1) plist[pbase + __popcll(mp & below)] = idx;
        pbase += __popcll(mp);
    }
    const int npos = pbase;  // wave-uniform
    __syncthreads();

    const int r0 = blockIdx.y * 32;
    if (r0 >= npos) return;
    const int c0 = blockIdx.x * 32;
    const int rl = lane & 15;
    const int koff = (lane >> 4) * 8;

    const int pr0 = min(r0 + rl, npos - 1);
    const int pr1 = min(r0 + 16 + rl, npos - 1);
    const float* A0 = pred + plist[pr0] * BS;
    const float* A1 = pred + plist[pr1] * BS;
    const float* B0 = pred + (c0 + rl) * BS;
    const float* B1 = pred + (c0 + 16 + rl) * BS;

    f32x4 acc00 = {0.f, 0.f, 0.f, 0.f};
    f32x4 acc01 = {0.f, 0.f, 0.f, 0.f};
    f32x4 acc10 = {0.f, 0.f, 0.f, 0.f};
    f32x4 acc11 = {0.f, 0.f, 0.f, 0.f};
    float na0 = 0.f, na1 = 0.f, nb0 = 0.f, nb1 = 0.f;

#pragma unroll 4
    for (int ks = 0; ks < 16; ++ks) {
        const int k = ks * 32 + koff;
        const f32x4 a0l = *(const f32x4*)(A0 + k);
        const f32x4 a0h = *(const f32x4*)(A0 + k + 4);
        const f32x4 a1l = *(const f32x4*)(A1 + k);
        const f32x4 a1h = *(const f32x4*)(A1 + k + 4);
        const f32x4 b0l = *(const f32x4*)(B0 + k);
        const f32x4 b0h = *(const f32x4*)(B0 + k + 4);
        const f32x4 b1l = *(const f32x4*)(B1 + k);
        const f32x4 b1h = *(const f32x4*)(B1 + k + 4);

        short8 sa0, sa1, sb0, sb1;
#pragma unroll
        for (int j = 0; j < 4; ++j) {
            na0 += a0l[j] * a0l[j] + a0h[j] * a0h[j];
            na1 += a1l[j] * a1l[j] + a1h[j] * a1h[j];
            nb0 += b0l[j] * b0l[j] + b0h[j] * b0h[j];
            nb1 += b1l[j] * b1l[j] + b1h[j] * b1h[j];
            sa0[j] = bf16_rne(a0l[j]); sa0[4 + j] = bf16_rne(a0h[j]);
            sa1[j] = bf16_rne(a1l[j]); sa1[4 + j] = bf16_rne(a1h[j]);
            sb0[j] = bf16_rne(b0l[j]); sb0[4 + j] = bf16_rne(b0h[j]);
            sb1[j] = bf16_rne(b1l[j]); sb1[4 + j] = bf16_rne(b1h[j]);
        }
        acc00 = __builtin_amdgcn_mfma_f32_16x16x32_bf16(sa0, sb0, acc00, 0, 0, 0);
        acc01 = __builtin_amdgcn_mfma_f32_16x16x32_bf16(sa0, sb1, acc01, 0, 0, 0);
        acc10 = __builtin_amdgcn_mfma_f32_16x16x32_bf16(sa1, sb0, acc10, 0, 0, 0);
        acc11 = __builtin_amdgcn_mfma_f32_16x16x32_bf16(sa1, sb1, acc11, 0, 0, 0);
    }

    na0 += __shfl_xor(na0, 16, 64); na0 += __shfl_xor(na0, 32, 64);
    na1 += __shfl_xor(na1, 16, 64); na1 += __shfl_xor(na1, 32, 64);
    nb0 += __shfl_xor(nb0, 16, 64); nb0 += __shfl_xor(nb0, 32, 64);
    nb1 += __shfl_xor(nb1, 16, 64); nb1 += __shfl_xor(nb1, 32, 64);
    const float ia0 = 1.0f / fmaxf(sqrtf(na0), 1e-10f);
    const float ia1 = 1.0f / fmaxf(sqrtf(na1), 1e-10f);
    const float ib0 = 1.0f / fmaxf(sqrtf(nb0), 1e-10f);
    const float ib1 = 1.0f / fmaxf(sqrtf(nb1), 1e-10f);

    // C/D layout: col = lane&15, row = (lane>>4)*4 + reg  [m89]
    const int rbase = (lane >> 4) * 4;
#pragma unroll
    for (int fr = 0; fr < 2; ++fr) {
        const float iaSel = (fr == 0) ? ia0 : ia1;
#pragma unroll
        for (int fc = 0; fc < 2; ++fc) {
            f32x4 v = (fr == 0) ? (fc == 0 ? acc00 : acc01) : (fc == 0 ? acc10 : acc11);
            const int col = c0 + fc * 16 + rl;
            const float icol = (fc == 0) ? ib0 : ib1;
#pragma unroll
            for (int r = 0; r < 4; ++r) {
                const float irow = __shfl(iaSel, rbase + r, 64);
                const int rowp = r0 + fr * 16 + rbase + r;  // pos-space row
                float d2 = 2.0f - 2.0f * v[r] * irow * icol;
                dist[rowp * BS + col] = sqrtf(fmaxf(d2, 0.f));
            }
        }
    }
}

// Kernel 2: block b = pos-space anchor. Wave 0 compacts pos/neg lists into LDS.
// Hinge via readlane j-broadcast + ballot count. Done-counter tail: last block
// reduces all 512 partials and writes out (fin was zeroed by kernel 1).
__global__ __launch_bounds__(256) void ktri(const float* __restrict__ dist,
                                            const int* __restrict__ target,
                                            float* __restrict__ psum,
                                            float* __restrict__ pcnt,
                                            unsigned int* __restrict__ fin,
                                            float* __restrict__ out) {
    const int b = blockIdx.x;
    const int tid = threadIdx.x;
    const int lane = tid & 63;
    const int w = tid >> 6;
    __shared__ int plist[BS];
    __shared__ int nlist[BS];
    __shared__ int cnts[2];
    __shared__ float sbuf[4];
    __shared__ float cbuf[4];
    __shared__ unsigned int slast;

    if (w == 0) {  // one-wave stable compaction into LDS
        int pbase = 0, nbase = 0;
        const unsigned long long below = (1ULL << lane) - 1ULL;
#pragma unroll
        for (int c = 0; c < 8; ++c) {
            const int idx = c * 64 + lane;
            const int tg = target[idx];
            const unsigned long long mp = __ballot(tg == 1);
            const unsigned long long mn = __ballot(tg == 0);
            if (tg == 1) plist[pbase + __popcll(mp & below)] = idx;
            else         nlist[nbase + __popcll(mn & below)] = idx;
            pbase += __popcll(mp);
            nbase += __popcll(mn);
        }
        if (lane == 0) { cnts[0] = pbase; cnts[1] = nbase; }
    }
    __syncthreads();
    const int npos = cnts[0];
    const int nneg = cnts[1];

    float sum = 0.f;
    unsigned int cw = 0;

    if (b < npos) {
        const float* drow = dist + b * BS;  // pos-space row
        // k-role: this thread's negatives (gathered), +1e30 pad
        const float bv0 = (tid < nneg) ? drow[nlist[tid]] : 1e30f;
        const float bv1 = (tid + 256 < nneg) ? drow[nlist[tid + 256]] : 1e30f;
        // j-role: wave w owns chunks w and w+4 of compacted positives
        const int ja = w * 64 + lane;
        const int jb2 = (w + 4) * 64 + lane;
        const float av0 = (ja < npos && ja != b) ? drow[plist[ja]] + MARGIN : -1e9f;
        const float av1 = (jb2 < npos && jb2 != b) ? drow[plist[jb2]] + MARGIN : -1e9f;

#define HINGE(TJ, BK)                                       \
    do {                                                    \
        const float v_ = (TJ) - (BK);                       \
        sum += fmaxf(v_, 0.f);                              \
        cw += (unsigned int)__popcll(__ballot(v_ > 0.f));   \
    } while (0)

        if (nneg > 256) {  // uniform rare path
            if (w * 64 < npos) {
#pragma unroll 8
                for (int jj = 0; jj < 64; ++jj) {
                    const float tj = __int_as_float(
                        __builtin_amdgcn_readlane(__float_as_int(av0), jj));
                    HINGE(tj, bv0); HINGE(tj, bv1);
                }
            }
            if ((w + 4) * 64 < npos) {
#pragma unroll 8
                for (int jj = 0; jj < 64; ++jj) {
                    const float tj = __int_as_float(
                        __builtin_amdgcn_readlane(__float_as_int(av1), jj));
                    HINGE(tj, bv0); HINGE(tj, bv1);
                }
            }
        } else {  // typical: nneg <= 256
            if (w * 64 < npos) {
#pragma unroll 8
                for (int jj = 0; jj < 64; ++jj) {
                    const float tj = __int_as_float(
                        __builtin_amdgcn_readlane(__float_as_int(av0), jj));
                    HINGE(tj, bv0);
                }
            }
            if ((w + 4) * 64 < npos) {
#pragma unroll 8
                for (int jj = 0; jj < 64; ++jj) {
                    const float tj = __int_as_float(
                        __builtin_amdgcn_readlane(__float_as_int(av1), jj));
                    HINGE(tj, bv0);
                }
            }
        }
#undef HINGE
    }

    float wsm = sum;
#pragma unroll
    for (int o = 32; o > 0; o >>= 1) wsm += __shfl_xor(wsm, o, 64);
    if (lane == 0) { sbuf[w] = wsm; cbuf[w] = (float)cw; }
    __syncthreads();
    if (tid == 0) {
        psum[b] = (sbuf[0] + sbuf[1]) + (sbuf[2] + sbuf[3]);
        pcnt[b] = (cbuf[0] + cbuf[1]) + (cbuf[2] + cbuf[3]);
        __threadfence();  // release partials
        slast = (atomicAdd(fin, 1u) == (unsigned int)(NBLK - 1)) ? 1u : 0u;
    }
    __syncthreads();
    if (slast != 0 && tid < 64) {
        __threadfence();  // acquire
        float s = 0.f, c = 0.f;
#pragma unroll
        for (int r = 0; r < 8; ++r) {
            s += psum[r * 64 + tid];
            c += pcnt[r * 64 + tid];
        }
#pragma unroll
        for (int o = 32; o > 0; o >>= 1) {
            s += __shfl_xor(s, o, 64);
            c += __shfl_xor(c, o, 64);
        }
        if (tid == 0) out[0] = s / (c + 1e-7f);
    }
}

extern "C" void kernel_launch(void* const* d_in, const int* in_sizes, int n_in,
                              void* d_out, int out_size, void* d_ws, size_t ws_size,
                              hipStream_t stream) {
    const float* pred = (const float*)d_in[0];
    const int* target = (const int*)d_in[1];
    float* out = (float*)d_out;
    char* base = (char*)d_ws;

    float* dist = (float*)base;               // 1 MB (pos-space rows)
    float* psum = (float*)(base + 1048576);   // 2 KB
    float* pcnt = (float*)(base + 1050624);   // 2 KB
    unsigned int* fin = (unsigned int*)(base + 1052672);

    dim3 gb(16, 16);
    kdistf<<<gb, 64, 0, stream>>>(pred, target, dist, fin);
    ktri<<<NBLK, 256, 0, stream>>>(dist, target, psum, pcnt, fin, out);
}